// Round 3
// baseline (237.033 us; speedup 1.0000x reference)
//
#include <hip/hip_runtime.h>
#include <hip/hip_bf16.h>
#include <math.h>

#define INDIM 768
#define NROWS 32768       // 8*4096
#define KSEL  38
#define NCOLS 76
#define HID   256
#define LN_EPS 1e-5f

typedef float  f32x4  __attribute__((ext_vector_type(4)));
typedef __bf16 bf16x8 __attribute__((ext_vector_type(8)));

#define MFMA16(a,b,c) __builtin_amdgcn_mfma_f32_16x16x32_bf16((a),(b),(c),0,0,0)

// ---- workspace: shared matrices pre-packed in MFMA B-fragment order ----
// frag value(lane, j) = M[n = nt*16 + (lane&15)][k = ks*32 + (lane>>4)*8 + j]
// BfP: DFT basis,  frag = kc*5 + nt   (kc 0..23, nt 0..4)   : 120 frags
// W1P: layer1 w,   frag = mlp*48 + nt*3 + ks (nt 0..15)     : 96 frags
// W2P: layer2 w,   frag = mlp*40 + nt*8 + ks (nt 0..4)      : 80 frags
// BsP: synth basis frag = nt*3 + ks  (nt 0..47)             : 144 frags
#define OFF_BFP 0
#define OFF_W1P 122880
#define OFF_W2P 221184
#define OFF_BSP 303104

__global__ void k_prep(const int* __restrict__ idxs,
                       const float* __restrict__ mu_w1, const float* __restrict__ sg_w1,
                       const float* __restrict__ mu_w2, const float* __restrict__ sg_w2,
                       __bf16* __restrict__ BfP, __bf16* __restrict__ W1P,
                       __bf16* __restrict__ W2P, __bf16* __restrict__ BsP)
{
    int tid = blockIdx.x * blockDim.x + threadIdx.x;
    int nth = gridDim.x * blockDim.x;
    const float TH = 6.28318530717958647692f / (float)INDIM;

    for (int e = tid; e < 120 * 512; e += nth) {
        int frag = e >> 9, lane = (e >> 3) & 63, j = e & 7;
        int kc = frag / 5, nt = frag % 5;
        int c = nt * 16 + (lane & 15);
        int k = kc * 32 + ((lane >> 4) << 3) + j;
        float v = 0.f;
        if (c < NCOLS) {
            int cc = (c < KSEL) ? c : c - KSEL;
            int f = idxs[cc];
            int m = (f * k) % INDIM;
            float s, co; sincosf(TH * (float)m, &s, &co);
            v = (c < KSEL) ? co : -s;
        }
        BfP[e] = (__bf16)v;
    }
    for (int e = tid; e < 96 * 512; e += nth) {
        int frag = e >> 9, lane = (e >> 3) & 63, j = e & 7;
        int mlp = frag / 48; int r = frag % 48;
        int nt = r / 3, ks = r % 3;
        int row = nt * 16 + (lane & 15);
        int k = ks * 32 + ((lane >> 4) << 3) + j;
        const float* W = mlp ? sg_w1 : mu_w1;
        W1P[e] = (__bf16)((k < NCOLS) ? W[row * NCOLS + k] : 0.f);
    }
    for (int e = tid; e < 80 * 512; e += nth) {
        int frag = e >> 9, lane = (e >> 3) & 63, j = e & 7;
        int mlp = frag / 40; int r = frag % 40;
        int nt = r / 8, ks = r % 8;
        int row = nt * 16 + (lane & 15);
        int k = ks * 32 + ((lane >> 4) << 3) + j;
        const float* W = mlp ? sg_w2 : mu_w2;
        W2P[e] = (__bf16)((row < NCOLS) ? W[row * HID + k] : 0.f);
    }
    for (int e = tid; e < 144 * 512; e += nth) {
        int frag = e >> 9, lane = (e >> 3) & 63, j = e & 7;
        int nt = frag / 3, ks = frag % 3;
        int n = nt * 16 + (lane & 15);
        int k = ks * 32 + ((lane >> 4) << 3) + j;
        float v = 0.f;
        if (k < NCOLS) {
            int cc = (k < KSEL) ? k : k - KSEL;
            int f = idxs[cc];
            int m = (f * n) % INDIM;
            float s, co; sincosf(TH * (float)m, &s, &co);
            v = ((k < KSEL) ? co : -s) * (2.0f / (float)INDIM);
        }
        BsP[e] = (__bf16)v;
    }
}

// tanh-form gelu (error vs exact ~3e-4 on gelu out -> ~5e-6 on final out)
static __device__ inline float gelu_fast(float v) {
    float u = v * (0.79788456080286535588f + 0.03567740813636141f * v * v);
    return v / (1.f + __expf(-2.f * u));
}

// cooperative async stage of two contiguous runs (one per p-half) of nkb KB
// each: unit u (1 KB) -> dst + u*1024, 8 waves round-robin (u % 8 == w).
// Global src per-lane (base + lane*16B), LDS dst wave-uniform (HW adds
// lane*16). Zero VGPR, counted in vmcnt, drained by __syncthreads().
static __device__ __forceinline__ void stage8(
    const __bf16* __restrict__ s0, const __bf16* __restrict__ s1,
    int nkb, char* dst, int w, int lane)
{
    typedef __attribute__((address_space(1))) const unsigned int g_u32;
    typedef __attribute__((address_space(3))) unsigned int l_u32;
    for (int u = w; u < 2 * nkb; u += 8) {
        const __bf16* s = (u < nkb) ? (s0 + (size_t)u * 512)
                                    : (s1 + (size_t)(u - nkb) * 512);
        __builtin_amdgcn_global_load_lds((g_u32*)(s + lane * 8),
                                         (l_u32*)(dst + u * 1024), 16, 0, 0);
    }
}

// 2-BLOCKS/CU fused kernel: 512 threads = 8 waves = 4 wave-pairs, 64 rows
// per block (4 tiles x 16), grid 512 -> 2 independent blocks/CU. The two
// resident blocks drift out of phase, so one block's MLP phases (LDS+VALU)
// overlap the other's DFT/synthesis phases (HBM) -- de-bursting HBM and
// covering barrier/vmcnt drains. Occupancy stays 16 waves/CU (register-
// pinned at V64+A64=128 -> 4 waves/SIMD; do NOT add registers).
// B streams double-buffered in R (2 x <=32 KB, 24-32 KB chunks).
// R overlays: PA f32[4][1280] at TOP of R (so next-phase chunk-0 staging
// into R[0..] overlaps the PA combine work); GW bf16 8x2176 at bottom.
// All overlays barrier-separated (see B-labels). LDS = 64K + 13K = 77 KB.
__global__ __launch_bounds__(512, 4) void k_fused(
    const float* __restrict__ x, const float* __restrict__ eps,
    const __bf16* __restrict__ Bf, const __bf16* __restrict__ W1f,
    const __bf16* __restrict__ W2f, const __bf16* __restrict__ Bs,
    const float* __restrict__ mu_b1, const float* __restrict__ mu_g,
    const float* __restrict__ mu_be, const float* __restrict__ mu_b2,
    const float* __restrict__ sg_b1, const float* __restrict__ sg_g,
    const float* __restrict__ sg_be, const float* __restrict__ sg_b2,
    float* __restrict__ out)
{
    __shared__ __align__(16) char   R[65536];        // staging DB / PA / GW
    __shared__ __align__(16) __bf16 tbuf[4][1664];   // per-tile 16x104 transpose buf
    float* PA = (float*)(R + 45056);                 // [4][1280] f32, top of R

    int tid = threadIdx.x;
    int w = tid >> 6, lane = tid & 63, q = lane >> 4, l16 = lane & 15;
    int t = w >> 1, p = w & 1;
    int rbase = blockIdx.x * 64 + t * 16;

    // ---------------- Phase 1: DFT, this wave does K-half p (12 kc) ----------
    // chunk c = 3 kk for both p = 30 KB (runs of 15 KB), 4 chunks, DB 2x30K.
    f32x4 acc[5] = {};
    {
        const float* xrow = x + (size_t)(rbase + l16) * INDIM + p * 384 + q * 8;
        stage8(Bf, Bf + (size_t)60 * 512, 15, R, w, lane);            // chunk 0
        float4 f0 = ((const float4*)xrow)[0];
        float4 f1 = ((const float4*)xrow)[1];
        __syncthreads();                              // chunk 0 ready
        #pragma unroll
        for (int c = 0; c < 4; ++c) {
            if (c < 3)
                stage8(Bf + (size_t)(15 * (c + 1)) * 512,
                       Bf + (size_t)(60 + 15 * (c + 1)) * 512,
                       15, R + ((c & 1) ^ 1) * 32768, w, lane);
            const char* cb = R + (c & 1) * 32768 + p * 15360 + (size_t)lane * 16;
            #pragma unroll
            for (int kkl = 0; kkl < 3; ++kkl) {
                int kk = c * 3 + kkl;
                float4 n0, n1;
                if (kk < 11) {                        // x prefetch 1 iter ahead
                    n0 = ((const float4*)(xrow + (kk + 1) * 32))[0];
                    n1 = ((const float4*)(xrow + (kk + 1) * 32))[1];
                }
                union { __bf16 h[8]; bf16x8 v; } a;
                a.h[0]=(__bf16)f0.x; a.h[1]=(__bf16)f0.y; a.h[2]=(__bf16)f0.z; a.h[3]=(__bf16)f0.w;
                a.h[4]=(__bf16)f1.x; a.h[5]=(__bf16)f1.y; a.h[6]=(__bf16)f1.z; a.h[7]=(__bf16)f1.w;
                #pragma unroll
                for (int nt = 0; nt < 5; ++nt) {
                    bf16x8 b = *(const bf16x8*)(cb + (kkl * 5 + nt) * 1024);
                    acc[nt] = MFMA16(a.v, b, acc[nt]);
                }
                if (kk < 11) { f0 = n0; f1 = n1; }
            }
            __syncthreads();   // chunk c consumed; chunk c+1 staged+drained
        }
    }
    // combine halves (fp32) via PA-top + transpose to A-layout in tbuf[t]
    if (p == 1) {
        #pragma unroll
        for (int nt = 0; nt < 5; ++nt)
            #pragma unroll
            for (int r = 0; r < 4; ++r)
                PA[t * 1280 + (q * 4 + r) * 80 + nt * 16 + l16] = acc[nt][r];
    }
    __syncthreads();                                  // B3: PA ready
    // W1 chunk 0 staged NOW into R[0,24K) -- disjoint from PA-top reads,
    // drains under the combine work at B4 (no serial stage stall).
    stage8(W1f, W1f + (size_t)48 * 512, 12, R, w, lane);
    if (p == 0) {
        #pragma unroll
        for (int nt = 0; nt < 5; ++nt)
            #pragma unroll
            for (int r = 0; r < 4; ++r) {
                float v = acc[nt][r] + PA[t * 1280 + (q * 4 + r) * 80 + nt * 16 + l16];
                tbuf[t][(q * 4 + r) * 104 + nt * 16 + l16] = (__bf16)v;
            }
        #pragma unroll
        for (int r = 0; r < 4; ++r)
            tbuf[t][(q * 4 + r) * 104 + 80 + l16] = (__bf16)0.f;
    }
    __syncthreads();                                  // B4: tbuf + W1 ch0 ready
    bf16x8 a1[3];
    #pragma unroll
    for (int ks = 0; ks < 3; ++ks)
        a1[ks] = *(const bf16x8*)&tbuf[t][l16 * 104 + ks * 32 + q * 8];

    // ---------------- Phase 2: this wave's MLP (mlp = p), layer1 -------------
    // chunk c = 4 nt both mlp = 24 KB (runs of 12 KB), 4 chunks.
    const float* b1 = p ? sg_b1 : mu_b1;
    const float* g  = p ? sg_g  : mu_g;
    const float* be = p ? sg_be : mu_be;

    f32x4 h[16] = {};
    #pragma unroll
    for (int c = 0; c < 4; ++c) {
        if (c < 3)
            stage8(W1f + (size_t)(12 * (c + 1)) * 512,
                   W1f + (size_t)(48 + 12 * (c + 1)) * 512,
                   12, R + ((c & 1) ^ 1) * 32768, w, lane);
        const char* cb = R + (c & 1) * 32768 + p * 12288 + (size_t)lane * 16;
        #pragma unroll
        for (int ntl = 0; ntl < 4; ++ntl)
            #pragma unroll
            for (int ks = 0; ks < 3; ++ks) {
                bf16x8 b = *(const bf16x8*)(cb + (ntl * 3 + ks) * 1024);
                h[4 * c + ntl] = MFMA16(a1[ks], b, h[4 * c + ntl]);
            }
        __syncthreads();
    }
    float s[4] = {}, ss[4] = {};
    #pragma unroll
    for (int nt = 0; nt < 16; ++nt) {
        float bb = b1[nt * 16 + l16];
        #pragma unroll
        for (int r = 0; r < 4; ++r) {
            float v = h[nt][r] + bb; h[nt][r] = v;
            s[r] += v; ss[r] += v * v;
        }
    }
    #pragma unroll
    for (int off = 1; off < 16; off <<= 1)
        #pragma unroll
        for (int r = 0; r < 4; ++r) {
            s[r] += __shfl_xor(s[r], off); ss[r] += __shfl_xor(ss[r], off);
        }
    float mean[4], rstd[4];
    #pragma unroll
    for (int r = 0; r < 4; ++r) {
        mean[r] = s[r] * (1.f / 256.f);
        rstd[r] = rsqrtf(ss[r] * (1.f / 256.f) - mean[r] * mean[r] + LN_EPS);
    }
    // LN + gelu -> wave-private buffer at R bottom (stride 136), 2 K-halves.
    // (W1 staging dead past last chunk barrier; gw is wave-private so no
    //  barrier needed between write and own read.)
    __bf16* gw = (__bf16*)R + w * 2176;
    bf16x8 a2[8];
    #pragma unroll
    for (int half = 0; half < 2; ++half) {
        #pragma unroll
        for (int ntl = 0; ntl < 8; ++ntl) {
            int nt = half * 8 + ntl;
            int i = nt * 16 + l16;
            float gv = g[i], bev = be[i];
            #pragma unroll
            for (int r = 0; r < 4; ++r)
                gw[(q * 4 + r) * 136 + ntl * 16 + l16] =
                    (__bf16)gelu_fast((h[nt][r] - mean[r]) * rstd[r] * gv + bev);
        }
        #pragma unroll
        for (int ks = 0; ks < 4; ++ks)
            a2[half * 4 + ks] = *(const bf16x8*)&gw[l16 * 136 + ks * 32 + q * 8];
    }
    __syncthreads();                                  // GW dead -> R reusable

    // ---------------- Phase 3: layer2 (this wave's MLP) ----------------------
    // chunk c: nt{2c,2c+1} both mlp = 32 KB; last chunk nt{4} = 16 KB.
    stage8(W2f, W2f + (size_t)40 * 512, 16, R, w, lane);
    __syncthreads();                                  // ch0 ready
    f32x4 o[5] = {};
    #pragma unroll
    for (int c = 0; c < 3; ++c) {
        if (c < 2) {
            int nkbn = (c == 1) ? 8 : 16;
            stage8(W2f + (size_t)(16 * (c + 1)) * 512,
                   W2f + (size_t)(40 + 16 * (c + 1)) * 512,
                   nkbn, R + ((c & 1) ^ 1) * 32768, w, lane);
        }
        int nkb = (c == 2) ? 8 : 16;
        int ntn = (c == 2) ? 1 : 2;
        const char* cb = R + (c & 1) * 32768 + p * (nkb * 1024) + (size_t)lane * 16;
        #pragma unroll
        for (int ntl = 0; ntl < 2; ++ntl) {
            if (ntl >= ntn) break;
            #pragma unroll
            for (int ks = 0; ks < 8; ++ks) {
                bf16x8 b = *(const bf16x8*)(cb + (ntl * 8 + ks) * 1024);
                o[2 * c + ntl] = MFMA16(a2[ks], b, o[2 * c + ntl]);
            }
        }
        __syncthreads();   // B9 on last iter: W2 dead -> PA-top/R[0..] free
    }

    // ---------------- Phase 4: z = (mu+b2m) + eps*(sg+b2s) -------------------
    // Bs chunk 0 staged NOW into R[0,24K): disjoint from PA-top and tbuf;
    // drains under ph4 work at B10 (no serial stage stall before ph5).
    stage8(Bs, Bs + (size_t)72 * 512, 12, R, w, lane);
    float ev[5][4];
    if (p == 0) {
        // publish o_mu to PA-top
        #pragma unroll
        for (int nt = 0; nt < 5; ++nt)
            #pragma unroll
            for (int r = 0; r < 4; ++r)
                PA[t * 1280 + (q * 4 + r) * 80 + nt * 16 + l16] = o[nt][r];
    } else {
        // prefetch eps
        #pragma unroll
        for (int nt = 0; nt < 5; ++nt) {
            int j = nt * 16 + l16;
            #pragma unroll
            for (int r = 0; r < 4; ++r)
                ev[nt][r] = (j < NCOLS)
                    ? eps[(size_t)(rbase + q * 4 + r) * NCOLS + j] : 0.f;
        }
    }
    __syncthreads();                                  // B10: PA(mu) + Bs ch0 ready
    if (p == 1) {
        #pragma unroll
        for (int nt = 0; nt < 5; ++nt) {
            int j = nt * 16 + l16;
            float b2m = (j < NCOLS) ? mu_b2[j] : 0.f;
            float b2s = (j < NCOLS) ? sg_b2[j] : 0.f;
            #pragma unroll
            for (int r = 0; r < 4; ++r) {
                float z = 0.f;
                if (j < NCOLS) {
                    float omu = PA[t * 1280 + (q * 4 + r) * 80 + j];
                    z = (omu + b2m) + ev[nt][r] * (o[nt][r] + b2s);
                }
                tbuf[t][(q * 4 + r) * 104 + j] = (__bf16)z;
            }
        }
        #pragma unroll
        for (int r = 0; r < 4; ++r)
            tbuf[t][(q * 4 + r) * 104 + 80 + l16] = (__bf16)0.f;
    }
    __syncthreads();                                  // B11: z ready, PA dead
    bf16x8 az[3];
    #pragma unroll
    for (int ks = 0; ks < 3; ++ks)
        az[ks] = *(const bf16x8*)&tbuf[t][l16 * 104 + ks * 32 + q * 8];

    // ---------------- Phase 5: synthesis, 24 n-tiles/wave --------------------
    // chunk c = 4 ntl both p = 24 KB (runs of 12 KB), 6 chunks.
    #pragma unroll
    for (int c = 0; c < 6; ++c) {
        if (c < 5)
            stage8(Bs + (size_t)(12 * (c + 1)) * 512,
                   Bs + (size_t)(72 + 12 * (c + 1)) * 512,
                   12, R + ((c & 1) ^ 1) * 32768, w, lane);
        const char* cb = R + (c & 1) * 32768 + p * 12288 + (size_t)lane * 16;
        #pragma unroll
        for (int ntl = 0; ntl < 4; ++ntl) {
            int nt = p * 24 + 4 * c + ntl;
            f32x4 oc = {};
            #pragma unroll
            for (int ks = 0; ks < 3; ++ks) {
                bf16x8 b = *(const bf16x8*)(cb + (ntl * 3 + ks) * 1024);
                oc = MFMA16(az[ks], b, oc);
            }
            #pragma unroll
            for (int r = 0; r < 4; ++r)
                out[(size_t)(rbase + q * 4 + r) * INDIM + nt * 16 + l16] = oc[r];
        }
        if (c < 5) __syncthreads();
    }
}

extern "C" void kernel_launch(void* const* d_in, const int* in_sizes, int n_in,
                              void* d_out, int out_size, void* d_ws, size_t ws_size,
                              hipStream_t stream)
{
    const float* x     = (const float*)d_in[0];
    const float* eps   = (const float*)d_in[1];
    const int*   idxs  = (const int*)  d_in[2];
    const float* mu_w1 = (const float*)d_in[3];
    const float* mu_b1 = (const float*)d_in[4];
    const float* mu_g  = (const float*)d_in[5];
    const float* mu_be = (const float*)d_in[6];
    const float* mu_w2 = (const float*)d_in[7];
    const float* mu_b2 = (const float*)d_in[8];
    const float* sg_w1 = (const float*)d_in[9];
    const float* sg_b1 = (const float*)d_in[10];
    const float* sg_g  = (const float*)d_in[11];
    const float* sg_be = (const float*)d_in[12];
    const float* sg_w2 = (const float*)d_in[13];
    const float* sg_b2 = (const float*)d_in[14];
    float* out = (float*)d_out;

    char* ws = (char*)d_ws;
    __bf16* BfP = (__bf16*)(ws + OFF_BFP);
    __bf16* W1P = (__bf16*)(ws + OFF_W1P);
    __bf16* W2P = (__bf16*)(ws + OFF_W2P);
    __bf16* BsP = (__bf16*)(ws + OFF_BSP);

    hipLaunchKernelGGL(k_prep, dim3(1024), dim3(256), 0, stream,
                       idxs, mu_w1, sg_w1, mu_w2, sg_w2, BfP, W1P, W2P, BsP);
    hipLaunchKernelGGL(k_fused, dim3(NROWS / 64), dim3(512), 0, stream,
                       x, eps, BfP, W1P, W2P, BsP,
                       mu_b1, mu_g, mu_be, mu_b2,
                       sg_b1, sg_g, sg_be, sg_b2, out);
}